// Round 6
// baseline (322.881 us; speedup 1.0000x reference)
//
#include <hip/hip_runtime.h>
#include <hip/hip_bf16.h>

#define S_LEN 2048
#define BATCH 4
#define EMB   1024
#define NH    16
#define HD    64
#define NROW  8192

// 0.125 * log2(e): folded into Q projection so softmax exp is a bare v_exp_f32
#define QSCALE 0.18033688011112043f

typedef __bf16 bf16x8 __attribute__((ext_vector_type(8)));
typedef float  f32x4  __attribute__((ext_vector_type(4)));

typedef __attribute__((address_space(3))) void lds_void;
typedef const __attribute__((address_space(1))) void gbl_void;
#define GLOAD_LDS16(g, l) __builtin_amdgcn_global_load_lds((gbl_void*)(g), (lds_void*)(l), 16, 0, 0)
#define MFMA16(a, b, c) __builtin_amdgcn_mfma_f32_16x16x32_bf16((a), (b), (c), 0, 0, 0)

#if __has_builtin(__builtin_amdgcn_exp2f)
#define EXP2(x) __builtin_amdgcn_exp2f(x)
#else
#define EXP2(x) __expf((x) * 0.6931471805599453f)
#endif

// ---------------- fp32 -> bf16 conversion ----------------
__global__ void cvt_bf16_kernel(const float* __restrict__ src,
                                __bf16* __restrict__ dst, int n4) {
    int i = blockIdx.x * blockDim.x + threadIdx.x;
    if (i >= n4) return;
    float4 v = ((const float4*)src)[i];
    union { __bf16 h[4]; short4 s4; } u;
    u.h[0] = (__bf16)v.x; u.h[1] = (__bf16)v.y;
    u.h[2] = (__bf16)v.z; u.h[3] = (__bf16)v.w;
    ((short4*)dst)[i] = u.s4;
}

// ---------------- fused QKV GEMM: 128x128 block tile ---------------------
__global__ __launch_bounds__(256) void gemm_qkv_kernel(
    const __bf16* __restrict__ A,
    const __bf16* __restrict__ W0, const __bf16* __restrict__ W1,
    const __bf16* __restrict__ W2,
    const float* __restrict__ bi0, const float* __restrict__ bi1,
    const float* __restrict__ bi2,
    __bf16* __restrict__ Qo, __bf16* __restrict__ Ko, __bf16* __restrict__ Vo)
{
    __shared__ __bf16 As[128 * 32];
    __shared__ __bf16 Bs[128 * 32];
    const int gid = blockIdx.x;
    const int mB = gid / 24, nB = gid % 24;
    const int which = nB >> 3;
    const __bf16* W = which == 0 ? W0 : (which == 1 ? W1 : W2);
    const float* bias = which == 0 ? bi0 : (which == 1 ? bi1 : bi2);
    __bf16* outb = which == 0 ? Qo : (which == 1 ? Ko : Vo);
    const int m0 = mB * 128;
    const int n0 = (nB & 7) * 128;

    const int lane = threadIdx.x & 63;
    const int wave = threadIdx.x >> 6;
    const int l15 = lane & 15;
    const int quad = lane >> 4;
    const int wm = (wave >> 1) * 64;
    const int wn = (wave & 1) * 64;

    const int c0 = wave * 128 + lane;
    const int c1 = c0 + 64;
    const int ar0 = c0 >> 2, ak0 = (c0 & 3) * 8;
    const int ar1 = c1 >> 2, ak1 = (c1 & 3) * 8;

    const __bf16* Ag = A + (size_t)m0 * EMB;
    const __bf16* Wg = W + (size_t)n0 * EMB;

    f32x4 acc[4][4];
#pragma unroll
    for (int i = 0; i < 4; ++i)
#pragma unroll
        for (int j = 0; j < 4; ++j) acc[i][j] = (f32x4){0.f, 0.f, 0.f, 0.f};

    for (int k0 = 0; k0 < EMB; k0 += 32) {
        __syncthreads();
        GLOAD_LDS16(Ag + (size_t)ar0 * EMB + k0 + ak0, As + wave * 1024);
        GLOAD_LDS16(Ag + (size_t)ar1 * EMB + k0 + ak1, As + wave * 1024 + 512);
        GLOAD_LDS16(Wg + (size_t)ar0 * EMB + k0 + ak0, Bs + wave * 1024);
        GLOAD_LDS16(Wg + (size_t)ar1 * EMB + k0 + ak1, Bs + wave * 1024 + 512);
        __syncthreads();

        bf16x8 af[4], bf[4];
#pragma unroll
        for (int t = 0; t < 4; ++t) {
            af[t] = *(const bf16x8*)(As + (wm + t * 16 + l15) * 32 + quad * 8);
            bf[t] = *(const bf16x8*)(Bs + (wn + t * 16 + l15) * 32 + quad * 8);
        }
#pragma unroll
        for (int i = 0; i < 4; ++i)
#pragma unroll
            for (int j = 0; j < 4; ++j)
                acc[i][j] = MFMA16(af[i], bf[j], acc[i][j]);
    }

#pragma unroll
    for (int j = 0; j < 4; ++j) {
        const int col = n0 + wn + j * 16 + l15;
        const float bv = bias[col];
        const int h = col >> 6, d = col & 63;
#pragma unroll
        for (int i = 0; i < 4; ++i) {
#pragma unroll
            for (int r = 0; r < 4; ++r) {
                const int m = m0 + wm + i * 16 + quad * 4 + r;
                float v = acc[i][j][r] + bv;
                if (which == 0) v *= QSCALE;   // fold softmax scale+log2e into Q
                const int b = m & 3, s = m >> 2;
                if (which == 2)
                    outb[((size_t)(b * NH + h) * HD + d) * S_LEN + s] = (__bf16)v;
                else
                    outb[((size_t)(b * NH + h) * S_LEN + s) * HD + d] = (__bf16)v;
            }
        }
    }
}

// ---------------- output projection GEMM (fp32 out) ----------------------
__global__ __launch_bounds__(256) void gemm_out_kernel(
    const __bf16* __restrict__ A, const __bf16* __restrict__ W,
    const float* __restrict__ bias, float* __restrict__ outf)
{
    __shared__ __bf16 As[128 * 32];
    __shared__ __bf16 Bs[128 * 32];
    const int lane = threadIdx.x & 63;
    const int wave = threadIdx.x >> 6;
    const int m0 = (blockIdx.x >> 3) * 128;
    const int n0 = (blockIdx.x & 7) * 128;
    const int l15 = lane & 15;
    const int quad = lane >> 4;
    const int wm = (wave >> 1) * 64;
    const int wn = (wave & 1) * 64;

    const int c0 = wave * 128 + lane;
    const int c1 = c0 + 64;
    const int ar0 = c0 >> 2, ak0 = (c0 & 3) * 8;
    const int ar1 = c1 >> 2, ak1 = (c1 & 3) * 8;

    const __bf16* Ag = A + (size_t)m0 * EMB;
    const __bf16* Wg = W + (size_t)n0 * EMB;

    f32x4 acc[4][4];
#pragma unroll
    for (int i = 0; i < 4; ++i)
#pragma unroll
        for (int j = 0; j < 4; ++j) acc[i][j] = (f32x4){0.f, 0.f, 0.f, 0.f};

    for (int k0 = 0; k0 < EMB; k0 += 32) {
        __syncthreads();
        GLOAD_LDS16(Ag + (size_t)ar0 * EMB + k0 + ak0, As + wave * 1024);
        GLOAD_LDS16(Ag + (size_t)ar1 * EMB + k0 + ak1, As + wave * 1024 + 512);
        GLOAD_LDS16(Wg + (size_t)ar0 * EMB + k0 + ak0, Bs + wave * 1024);
        GLOAD_LDS16(Wg + (size_t)ar1 * EMB + k0 + ak1, Bs + wave * 1024 + 512);
        __syncthreads();

        bf16x8 af[4], bf[4];
#pragma unroll
        for (int t = 0; t < 4; ++t) {
            af[t] = *(const bf16x8*)(As + (wm + t * 16 + l15) * 32 + quad * 8);
            bf[t] = *(const bf16x8*)(Bs + (wn + t * 16 + l15) * 32 + quad * 8);
        }
#pragma unroll
        for (int i = 0; i < 4; ++i)
#pragma unroll
            for (int j = 0; j < 4; ++j)
                acc[i][j] = MFMA16(af[i], bf[j], acc[i][j]);
    }

#pragma unroll
    for (int j = 0; j < 4; ++j) {
        const int col = n0 + wn + j * 16 + l15;
        const float bv = bias[col];
#pragma unroll
        for (int i = 0; i < 4; ++i)
#pragma unroll
            for (int r = 0; r < 4; ++r) {
                const int m = m0 + wm + i * 16 + quad * 4 + r;
                outf[(size_t)m * EMB + col] = acc[i][j][r] + bv;
            }
    }
}

// ---------------- Flash attention v5 -------------------------------------
// 2 waves x 64 Q-rows per block (grid 16x64). Tc=32 K/V tiles double-
// buffered in LDS (26.6 KB). kf/vf ds_read_b128 now amortize over 4 mi
// row-tiles: per iter 12 b128 + 16 b32 feed 36 MFMAs (was 10+8 for 14).
// Q pre-scaled by 0.125*log2e -> p = exp2(s). Row sums via MFMA(ones).
__global__ __launch_bounds__(128, 2) void attn_kernel(
    const __bf16* __restrict__ Q, const __bf16* __restrict__ Kp,
    const __bf16* __restrict__ Vt, __bf16* __restrict__ Ao)
{
    __shared__ __align__(16) __bf16 Ks[2][32 * 64];  // [t][d swizzled] 4KB ea
    __shared__ __align__(16) __bf16 Vs[2][32 * 64];  // [d][t swizzled] 4KB ea
    __shared__ __align__(16) __bf16 Ps[2][64 * 40];  // per-wave P, stride 40

    const int tid = threadIdx.x;           // 0..127
    const int lane = tid & 63;
    const int wave = tid >> 6;             // 0..1
    const int l15 = lane & 15;
    const int quad = lane >> 4;
    const int bh = blockIdx.y;
    const int b = bh >> 4, h = bh & 15;
    const int qw = blockIdx.x * 128 + wave * 64;

    const __bf16* Qb = Q  + (size_t)bh * S_LEN * HD;
    const __bf16* Kb = Kp + (size_t)bh * S_LEN * HD;
    const __bf16* Vb = Vt + (size_t)bh * HD * S_LEN;

    // staging: 256 16B chunks per tile; this thread does chunks tid, tid+128.
    // K chunk c: row c>>3, src d-chunk (c&7)^((row>>1)&7)  (phys slot c&7)
    const int c0 = tid, c1 = tid + 128;
    const int kr0 = c0 >> 3, ks0 = ((c0 & 7) ^ ((c0 >> 4) & 7)) * 8;
    const int kr1 = c1 >> 3, ks1 = ((c1 & 7) ^ ((c1 >> 4) & 7)) * 8;
    // V chunk c: row c>>2, src t-chunk (c&3)^((row>>1)&3)
    const int vr0 = c0 >> 2, vs0 = ((c0 & 3) ^ ((c0 >> 3) & 3)) * 8;
    const int vr1 = c1 >> 2, vs1 = ((c1 & 3) ^ ((c1 >> 3) & 3)) * 8;

    bf16x8 qf[4][2];
#pragma unroll
    for (int mi = 0; mi < 4; ++mi)
#pragma unroll
        for (int kc = 0; kc < 2; ++kc)
            qf[mi][kc] = *(const bf16x8*)(Qb + (size_t)(qw + mi * 16 + l15) * HD
                                          + kc * 32 + quad * 8);

    bf16x8 ones;
#pragma unroll
    for (int i = 0; i < 8; ++i) ones[i] = (__bf16)1.0f;

    f32x4 acco[4][4], accl[4];
#pragma unroll
    for (int mi = 0; mi < 4; ++mi) {
        accl[mi] = (f32x4){0.f, 0.f, 0.f, 0.f};
#pragma unroll
        for (int nt = 0; nt < 4; ++nt) acco[mi][nt] = (f32x4){0.f, 0.f, 0.f, 0.f};
    }

    // fire tile 0
    GLOAD_LDS16(Kb + (size_t)kr0 * HD + ks0, &Ks[0][c0 * 8]);
    GLOAD_LDS16(Kb + (size_t)kr1 * HD + ks1, &Ks[0][c1 * 8]);
    GLOAD_LDS16(Vb + (size_t)vr0 * S_LEN + vs0, &Vs[0][c0 * 8]);
    GLOAD_LDS16(Vb + (size_t)vr1 * S_LEN + vs1, &Vs[0][c1 * 8]);

    for (int it = 0; it < S_LEN / 32; ++it) {
        const int bi = it & 1;
        __syncthreads();            // drains prefetch fired last iter + frees bi^1
        if (it + 1 < S_LEN / 32) {
            const int t0 = (it + 1) * 32;
            GLOAD_LDS16(Kb + (size_t)(t0 + kr0) * HD + ks0, &Ks[bi ^ 1][c0 * 8]);
            GLOAD_LDS16(Kb + (size_t)(t0 + kr1) * HD + ks1, &Ks[bi ^ 1][c1 * 8]);
            GLOAD_LDS16(Vb + (size_t)vr0 * S_LEN + t0 + vs0, &Vs[bi ^ 1][c0 * 8]);
            GLOAD_LDS16(Vb + (size_t)vr1 * S_LEN + t0 + vs1, &Vs[bi ^ 1][c1 * 8]);
        }
        const __bf16* Kt = &Ks[bi][0];
        const __bf16* Vl = &Vs[bi][0];
        __bf16* Pw = &Ps[wave][0];

        // K fragments: even/odd t-pairs (cols 2*l15, 2*l15+1), shared by all mi
        bf16x8 kf[2][2];
#pragma unroll
        for (int p = 0; p < 2; ++p) {
            const int r = 2 * l15 + p;
            const int x = l15 & 7;          // (r>>1)&7
#pragma unroll
            for (int kc = 0; kc < 2; ++kc)
                kf[p][kc] = *(const bf16x8*)(Kt + r * 64 + (((kc * 4 + quad) ^ x) << 3));
        }
#pragma unroll
        for (int mi = 0; mi < 4; ++mi) {
            f32x4 se = {0.f, 0.f, 0.f, 0.f}, so = {0.f, 0.f, 0.f, 0.f};
            se = MFMA16(qf[mi][0], kf[0][0], se);
            se = MFMA16(qf[mi][1], kf[0][1], se);
            so = MFMA16(qf[mi][0], kf[1][0], so);
            so = MFMA16(qf[mi][1], kf[1][1], so);
#pragma unroll
            for (int r = 0; r < 4; ++r) {
                float pe = EXP2(se[r]);     // Q pre-scaled: s already *0.125*log2e
                float po = EXP2(so[r]);
                union { __bf16 hh[2]; unsigned u; } pk;
                pk.hh[0] = (__bf16)pe;
                pk.hh[1] = (__bf16)po;
                *(unsigned*)(Pw + (mi * 16 + quad * 4 + r) * 40 + 2 * l15) = pk.u;
            }
        }
        // P (64x32) -> A-frags; lsum via MFMA(ones); PV
        bf16x8 pf[4];
#pragma unroll
        for (int mi = 0; mi < 4; ++mi) {
            pf[mi] = *(const bf16x8*)(Pw + (mi * 16 + l15) * 40 + quad * 8);
            accl[mi] = MFMA16(pf[mi], ones, accl[mi]);
        }
#pragma unroll
        for (int nt = 0; nt < 4; ++nt) {
            const int rv = nt * 16 + l15;
            const int xv = (l15 >> 1) & 3;  // (rv>>1)&3
            bf16x8 vf = *(const bf16x8*)(Vl + rv * 32 + ((quad ^ xv) << 3));
#pragma unroll
            for (int mi = 0; mi < 4; ++mi)
                acco[mi][nt] = MFMA16(pf[mi], vf, acco[mi][nt]);
        }
    }

    // normalize: accl rows (quad*4+r) match acco rows exactly; no reduce needed
#pragma unroll
    for (int mi = 0; mi < 4; ++mi)
#pragma unroll
        for (int r = 0; r < 4; ++r) {
            const float inv = 1.0f / accl[mi][r];
            const int srow = qw + mi * 16 + quad * 4 + r;
            const int n = srow * BATCH + b;
#pragma unroll
            for (int nt = 0; nt < 4; ++nt)
                Ao[(size_t)n * EMB + h * 64 + nt * 16 + l15] =
                    (__bf16)(acco[mi][nt][r] * inv);
        }
}

// ---------------- host launch ----------------
extern "C" void kernel_launch(void* const* d_in, const int* in_sizes, int n_in,
                              void* d_out, int out_size, void* d_ws, size_t ws_size,
                              hipStream_t stream) {
    const float* x  = (const float*)d_in[0];
    const float* Wq = (const float*)d_in[1];
    const float* bq = (const float*)d_in[2];
    const float* Wk = (const float*)d_in[3];
    const float* bk = (const float*)d_in[4];
    const float* Wv = (const float*)d_in[5];
    const float* bv = (const float*)d_in[6];
    const float* Wo = (const float*)d_in[7];
    const float* bo = (const float*)d_in[8];
    float* out = (float*)d_out;

    char* ws = (char*)d_ws;
    const size_t xbf_sz = (size_t)NROW * EMB * 2;
    const size_t wbf_sz = (size_t)EMB * EMB * 2;
    const size_t qkv_sz = (size_t)BATCH * NH * S_LEN * HD * 2;
    __bf16* x_bf  = (__bf16*)ws;  ws += xbf_sz;
    __bf16* Wq_bf = (__bf16*)ws;  ws += wbf_sz;
    __bf16* Wk_bf = (__bf16*)ws;  ws += wbf_sz;
    __bf16* Wv_bf = (__bf16*)ws;  ws += wbf_sz;
    __bf16* Wo_bf = (__bf16*)ws;  ws += wbf_sz;
    __bf16* Qb    = (__bf16*)ws;  ws += qkv_sz;
    __bf16* Kb    = (__bf16*)ws;  ws += qkv_sz;
    __bf16* Vtb   = (__bf16*)ws;  ws += qkv_sz;
    __bf16* Aob   = (__bf16*)ws;  ws += qkv_sz;

    {
        int n4 = NROW * EMB / 4;
        cvt_bf16_kernel<<<(n4 + 255) / 256, 256, 0, stream>>>(x, x_bf, n4);
        int w4 = EMB * EMB / 4;
        cvt_bf16_kernel<<<(w4 + 255) / 256, 256, 0, stream>>>(Wq, Wq_bf, w4);
        cvt_bf16_kernel<<<(w4 + 255) / 256, 256, 0, stream>>>(Wk, Wk_bf, w4);
        cvt_bf16_kernel<<<(w4 + 255) / 256, 256, 0, stream>>>(Wv, Wv_bf, w4);
        cvt_bf16_kernel<<<(w4 + 255) / 256, 256, 0, stream>>>(Wo, Wo_bf, w4);
    }
    gemm_qkv_kernel<<<64 * 24, 256, 0, stream>>>(x_bf, Wq_bf, Wk_bf, Wv_bf,
                                                 bq, bk, bv, Qb, Kb, Vtb);
    dim3 ag(S_LEN / 128, BATCH * NH);
    attn_kernel<<<ag, 128, 0, stream>>>(Qb, Kb, Vtb, Aob);
    gemm_out_kernel<<<(NROW / 128) * (EMB / 128), 256, 0, stream>>>(Aob, Wo_bf, bo, out);
}

// Round 7
// 312.171 us; speedup vs baseline: 1.0343x; 1.0343x over previous
//
#include <hip/hip_runtime.h>
#include <hip/hip_bf16.h>

#define S_LEN 2048
#define BATCH 4
#define EMB   1024
#define NH    16
#define HD    64
#define NROW  8192

// 0.125 * log2(e): folded into Q projection so softmax exp is a bare v_exp_f32
#define QSCALE 0.18033688011112043f

typedef __bf16 bf16x8 __attribute__((ext_vector_type(8)));
typedef float  f32x4  __attribute__((ext_vector_type(4)));

typedef __attribute__((address_space(3))) void lds_void;
typedef const __attribute__((address_space(1))) void gbl_void;
#define GLOAD_LDS16(g, l) __builtin_amdgcn_global_load_lds((gbl_void*)(g), (lds_void*)(l), 16, 0, 0)
#define MFMA16(a, b, c) __builtin_amdgcn_mfma_f32_16x16x32_bf16((a), (b), (c), 0, 0, 0)

#if __has_builtin(__builtin_amdgcn_exp2f)
#define EXP2(x) __builtin_amdgcn_exp2f(x)
#else
#define EXP2(x) __expf((x) * 0.6931471805599453f)
#endif

// ---------------- fused fp32 -> bf16 conversion (all 5 tensors) ----------
__global__ __launch_bounds__(256) void cvt_all_kernel(
    const float* __restrict__ x,  const float* __restrict__ Wq,
    const float* __restrict__ Wk, const float* __restrict__ Wv,
    const float* __restrict__ Wo,
    __bf16* __restrict__ xb, __bf16* __restrict__ qb, __bf16* __restrict__ kb,
    __bf16* __restrict__ vb, __bf16* __restrict__ ob)
{
    const int gid = blockIdx.x;
    const float* src; __bf16* dst; int i;
    if (gid < 8192) {                       // x: 8.39M elems / 4 = 2.1M float4
        src = x; dst = xb; i = gid * 256 + threadIdx.x;
    } else {
        const int g = gid - 8192;           // weights: 262144 float4 each
        const int seg = g >> 10;
        src = seg == 0 ? Wq : seg == 1 ? Wk : seg == 2 ? Wv : Wo;
        dst = seg == 0 ? qb : seg == 1 ? kb : seg == 2 ? vb : ob;
        i = (g & 1023) * 256 + threadIdx.x;
    }
    float4 v = ((const float4*)src)[i];
    union { __bf16 h[4]; short4 s4; } u;
    u.h[0] = (__bf16)v.x; u.h[1] = (__bf16)v.y;
    u.h[2] = (__bf16)v.z; u.h[3] = (__bf16)v.w;
    ((short4*)dst)[i] = u.s4;
}

// ---------------- fused QKV GEMM: 128x128 block tile ---------------------
__global__ __launch_bounds__(256) void gemm_qkv_kernel(
    const __bf16* __restrict__ A,
    const __bf16* __restrict__ W0, const __bf16* __restrict__ W1,
    const __bf16* __restrict__ W2,
    const float* __restrict__ bi0, const float* __restrict__ bi1,
    const float* __restrict__ bi2,
    __bf16* __restrict__ Qo, __bf16* __restrict__ Ko, __bf16* __restrict__ Vo)
{
    __shared__ __bf16 As[128 * 32];
    __shared__ __bf16 Bs[128 * 32];
    const int gid = blockIdx.x;
    const int mB = gid / 24, nB = gid % 24;
    const int which = nB >> 3;
    const __bf16* W = which == 0 ? W0 : (which == 1 ? W1 : W2);
    const float* bias = which == 0 ? bi0 : (which == 1 ? bi1 : bi2);
    __bf16* outb = which == 0 ? Qo : (which == 1 ? Ko : Vo);
    const int m0 = mB * 128;
    const int n0 = (nB & 7) * 128;

    const int lane = threadIdx.x & 63;
    const int wave = threadIdx.x >> 6;
    const int l15 = lane & 15;
    const int quad = lane >> 4;
    const int wm = (wave >> 1) * 64;
    const int wn = (wave & 1) * 64;

    const int c0 = wave * 128 + lane;
    const int c1 = c0 + 64;
    const int ar0 = c0 >> 2, ak0 = (c0 & 3) * 8;
    const int ar1 = c1 >> 2, ak1 = (c1 & 3) * 8;

    const __bf16* Ag = A + (size_t)m0 * EMB;
    const __bf16* Wg = W + (size_t)n0 * EMB;

    f32x4 acc[4][4];
#pragma unroll
    for (int i = 0; i < 4; ++i)
#pragma unroll
        for (int j = 0; j < 4; ++j) acc[i][j] = (f32x4){0.f, 0.f, 0.f, 0.f};

    for (int k0 = 0; k0 < EMB; k0 += 32) {
        __syncthreads();
        GLOAD_LDS16(Ag + (size_t)ar0 * EMB + k0 + ak0, As + wave * 1024);
        GLOAD_LDS16(Ag + (size_t)ar1 * EMB + k0 + ak1, As + wave * 1024 + 512);
        GLOAD_LDS16(Wg + (size_t)ar0 * EMB + k0 + ak0, Bs + wave * 1024);
        GLOAD_LDS16(Wg + (size_t)ar1 * EMB + k0 + ak1, Bs + wave * 1024 + 512);
        __syncthreads();

        bf16x8 af[4], bf[4];
#pragma unroll
        for (int t = 0; t < 4; ++t) {
            af[t] = *(const bf16x8*)(As + (wm + t * 16 + l15) * 32 + quad * 8);
            bf[t] = *(const bf16x8*)(Bs + (wn + t * 16 + l15) * 32 + quad * 8);
        }
#pragma unroll
        for (int i = 0; i < 4; ++i)
#pragma unroll
            for (int j = 0; j < 4; ++j)
                acc[i][j] = MFMA16(af[i], bf[j], acc[i][j]);
    }

#pragma unroll
    for (int j = 0; j < 4; ++j) {
        const int col = n0 + wn + j * 16 + l15;
        const float bv = bias[col];
        const int h = col >> 6, d = col & 63;
#pragma unroll
        for (int i = 0; i < 4; ++i) {
#pragma unroll
            for (int r = 0; r < 4; ++r) {
                const int m = m0 + wm + i * 16 + quad * 4 + r;
                float v = acc[i][j][r] + bv;
                if (which == 0) v *= QSCALE;   // fold softmax scale+log2e into Q
                const int b = m & 3, s = m >> 2;
                if (which == 2)
                    outb[((size_t)(b * NH + h) * HD + d) * S_LEN + s] = (__bf16)v;
                else
                    outb[((size_t)(b * NH + h) * S_LEN + s) * HD + d] = (__bf16)v;
            }
        }
    }
}

// ---------------- output projection GEMM (fp32 out) ----------------------
__global__ __launch_bounds__(256) void gemm_out_kernel(
    const __bf16* __restrict__ A, const __bf16* __restrict__ W,
    const float* __restrict__ bias, float* __restrict__ outf)
{
    __shared__ __bf16 As[128 * 32];
    __shared__ __bf16 Bs[128 * 32];
    const int lane = threadIdx.x & 63;
    const int wave = threadIdx.x >> 6;
    const int m0 = (blockIdx.x >> 3) * 128;
    const int n0 = (blockIdx.x & 7) * 128;
    const int l15 = lane & 15;
    const int quad = lane >> 4;
    const int wm = (wave >> 1) * 64;
    const int wn = (wave & 1) * 64;

    const int c0 = wave * 128 + lane;
    const int c1 = c0 + 64;
    const int ar0 = c0 >> 2, ak0 = (c0 & 3) * 8;
    const int ar1 = c1 >> 2, ak1 = (c1 & 3) * 8;

    const __bf16* Ag = A + (size_t)m0 * EMB;
    const __bf16* Wg = W + (size_t)n0 * EMB;

    f32x4 acc[4][4];
#pragma unroll
    for (int i = 0; i < 4; ++i)
#pragma unroll
        for (int j = 0; j < 4; ++j) acc[i][j] = (f32x4){0.f, 0.f, 0.f, 0.f};

    for (int k0 = 0; k0 < EMB; k0 += 32) {
        __syncthreads();
        GLOAD_LDS16(Ag + (size_t)ar0 * EMB + k0 + ak0, As + wave * 1024);
        GLOAD_LDS16(Ag + (size_t)ar1 * EMB + k0 + ak1, As + wave * 1024 + 512);
        GLOAD_LDS16(Wg + (size_t)ar0 * EMB + k0 + ak0, Bs + wave * 1024);
        GLOAD_LDS16(Wg + (size_t)ar1 * EMB + k0 + ak1, Bs + wave * 1024 + 512);
        __syncthreads();

        bf16x8 af[4], bf[4];
#pragma unroll
        for (int t = 0; t < 4; ++t) {
            af[t] = *(const bf16x8*)(As + (wm + t * 16 + l15) * 32 + quad * 8);
            bf[t] = *(const bf16x8*)(Bs + (wn + t * 16 + l15) * 32 + quad * 8);
        }
#pragma unroll
        for (int i = 0; i < 4; ++i)
#pragma unroll
            for (int j = 0; j < 4; ++j)
                acc[i][j] = MFMA16(af[i], bf[j], acc[i][j]);
    }

#pragma unroll
    for (int j = 0; j < 4; ++j) {
        const int col = n0 + wn + j * 16 + l15;
        const float bv = bias[col];
#pragma unroll
        for (int i = 0; i < 4; ++i)
#pragma unroll
            for (int r = 0; r < 4; ++r) {
                const int m = m0 + wm + i * 16 + quad * 4 + r;
                outf[(size_t)m * EMB + col] = acc[i][j][r] + bv;
            }
    }
}

// ---------------- Flash attention v6 -------------------------------------
// Block = 4 waves = (2 row-halves x 2 t-halves). Each wave: 64 Q-rows x
// 1024 t. No-max softmax => acco/accl are additive over t; t-half partials
// combined through LDS at the end (reusing K/V buffers). 4096 waves total
// (12/CU at 52 KB LDS). S^T = K*Q^T formulation: C-layout holds 4
// contiguous t per lane -> P written as 8 ds_write_b64 (was 16 b32).
__global__ __launch_bounds__(256, 3) void attn_kernel(
    const __bf16* __restrict__ Q, const __bf16* __restrict__ Kp,
    const __bf16* __restrict__ Vt, __bf16* __restrict__ Ao)
{
    __shared__ __align__(16) __bf16 Ks[2][2][32 * 64];  // [thalf][buf][t][d sw]
    __shared__ __align__(16) __bf16 Vs[2][2][32 * 64];  // [thalf][buf][d][t sw]
    __shared__ __align__(16) __bf16 Ps[4][64 * 40];     // per-wave P [m][t]

    const int tid = threadIdx.x;
    const int lane = tid & 63;
    const int wave = tid >> 6;             // 0..3
    const int th = wave >> 1;              // t-half
    const int wr = wave & 1;               // row-half
    const int l15 = lane & 15;
    const int quad = lane >> 4;
    const int bh = blockIdx.y;
    const int b = bh >> 4, h = bh & 15;
    const int qw = blockIdx.x * 128 + wr * 64;
    const int tbase = th * (S_LEN / 2);

    const __bf16* Qb = Q  + (size_t)bh * S_LEN * HD;
    const __bf16* Kb = Kp + (size_t)bh * S_LEN * HD;
    const __bf16* Vb = Vt + (size_t)bh * HD * S_LEN;

    // staging (per t-half: 128 threads stage 512 chunks, 4 per thread)
    const int ltid = tid & 127;
    const int c0 = ltid, c1 = ltid + 128;
    const int kr0 = c0 >> 3, ks0 = ((c0 & 7) ^ ((c0 >> 4) & 7)) * 8;
    const int kr1 = c1 >> 3, ks1 = ((c1 & 7) ^ ((c1 >> 4) & 7)) * 8;
    const int vr0 = c0 >> 2, vs0 = ((c0 & 3) ^ ((c0 >> 3) & 3)) * 8;
    const int vr1 = c1 >> 2, vs1 = ((c1 & 3) ^ ((c1 >> 3) & 3)) * 8;

    bf16x8 qf[4][2];
#pragma unroll
    for (int mi = 0; mi < 4; ++mi)
#pragma unroll
        for (int kc = 0; kc < 2; ++kc)
            qf[mi][kc] = *(const bf16x8*)(Qb + (size_t)(qw + mi * 16 + l15) * HD
                                          + kc * 32 + quad * 8);

    bf16x8 ones;
#pragma unroll
    for (int i = 0; i < 8; ++i) ones[i] = (__bf16)1.0f;

    f32x4 acco[4][4], accl[4];
#pragma unroll
    for (int mi = 0; mi < 4; ++mi) {
        accl[mi] = (f32x4){0.f, 0.f, 0.f, 0.f};
#pragma unroll
        for (int nt = 0; nt < 4; ++nt) acco[mi][nt] = (f32x4){0.f, 0.f, 0.f, 0.f};
    }

    // fire tile 0 of this wave's t-half
    GLOAD_LDS16(Kb + (size_t)(tbase + kr0) * HD + ks0, &Ks[th][0][c0 * 8]);
    GLOAD_LDS16(Kb + (size_t)(tbase + kr1) * HD + ks1, &Ks[th][0][c1 * 8]);
    GLOAD_LDS16(Vb + (size_t)vr0 * S_LEN + tbase + vs0, &Vs[th][0][c0 * 8]);
    GLOAD_LDS16(Vb + (size_t)vr1 * S_LEN + tbase + vs1, &Vs[th][0][c1 * 8]);

    for (int it = 0; it < S_LEN / 64; ++it) {   // 32 iters of 32 t each
        const int bi = it & 1;
        __syncthreads();        // drains prefetch fired last iter + frees bi^1
        if (it + 1 < S_LEN / 64) {
            const int t0 = tbase + (it + 1) * 32;
            GLOAD_LDS16(Kb + (size_t)(t0 + kr0) * HD + ks0, &Ks[th][bi ^ 1][c0 * 8]);
            GLOAD_LDS16(Kb + (size_t)(t0 + kr1) * HD + ks1, &Ks[th][bi ^ 1][c1 * 8]);
            GLOAD_LDS16(Vb + (size_t)vr0 * S_LEN + t0 + vs0, &Vs[th][bi ^ 1][c0 * 8]);
            GLOAD_LDS16(Vb + (size_t)vr1 * S_LEN + t0 + vs1, &Vs[th][bi ^ 1][c1 * 8]);
        }
        const __bf16* Kt = &Ks[th][bi][0];
        const __bf16* Vl = &Vs[th][bi][0];
        __bf16* Pw = &Ps[wave][0];

        // K A-fragments: row t = ti*16 + l15, k = d
        bf16x8 kf[2][2];
        const int x = (l15 >> 1) & 7;
#pragma unroll
        for (int ti = 0; ti < 2; ++ti)
#pragma unroll
            for (int kc = 0; kc < 2; ++kc)
                kf[ti][kc] = *(const bf16x8*)(Kt + (ti * 16 + l15) * 64
                                              + (((kc * 4 + quad) ^ x) << 3));

        // S^T = K * Q^T: D[t][m], lane holds m = l15, t = ti*16+quad*4+r
        // -> 4 contiguous t per lane: one b64 write into P[m][t]
#pragma unroll
        for (int mj = 0; mj < 4; ++mj) {
#pragma unroll
            for (int ti = 0; ti < 2; ++ti) {
                f32x4 st = {0.f, 0.f, 0.f, 0.f};
                st = MFMA16(kf[ti][0], qf[mj][0], st);
                st = MFMA16(kf[ti][1], qf[mj][1], st);
                union { __bf16 hh[4]; uint2 u2; } pk;
#pragma unroll
                for (int r = 0; r < 4; ++r) pk.hh[r] = (__bf16)EXP2(st[r]);
                *(uint2*)(Pw + (mj * 16 + l15) * 40 + ti * 16 + quad * 4) = pk.u2;
            }
        }
        // P -> A-frags; lsum via MFMA(ones); PV  (wave-local, no barrier)
        bf16x8 pf[4];
#pragma unroll
        for (int mi = 0; mi < 4; ++mi) {
            pf[mi] = *(const bf16x8*)(Pw + (mi * 16 + l15) * 40 + quad * 8);
            accl[mi] = MFMA16(pf[mi], ones, accl[mi]);
        }
#pragma unroll
        for (int nt = 0; nt < 4; ++nt) {
            const int rv = nt * 16 + l15;
            const int xv = (l15 >> 1) & 3;
            bf16x8 vf = *(const bf16x8*)(Vl + rv * 32 + ((quad ^ xv) << 3));
#pragma unroll
            for (int mi = 0; mi < 4; ++mi)
                acco[mi][nt] = MFMA16(pf[mi], vf, acco[mi][nt]);
        }
    }

    // combine t-halves through LDS (reuse K/V buffers; 16 KB per dump)
    __syncthreads();
    if (th == 1) {
        float* dA = (wr == 0) ? (float*)&Ks[0][0][0] : (float*)&Vs[0][0][0];
#pragma unroll
        for (int mi = 0; mi < 4; ++mi)
#pragma unroll
            for (int nt = 0; nt < 4; ++nt)
                *(f32x4*)(dA + ((mi * 4 + nt) * 64 + lane) * 4) = acco[mi][nt];
        float* dL = (float*)&Ps[wave][0];
#pragma unroll
        for (int mi = 0; mi < 4; ++mi)
            *(f32x4*)(dL + lane * 16 + mi * 4) = accl[mi];
    }
    __syncthreads();
    if (th == 0) {
        float* dA = (wr == 0) ? (float*)&Ks[0][0][0] : (float*)&Vs[0][0][0];
        float* dL = (float*)&Ps[wave + 2][0];
#pragma unroll
        for (int mi = 0; mi < 4; ++mi)
            accl[mi] += *(const f32x4*)(dL + lane * 16 + mi * 4);
#pragma unroll
        for (int mi = 0; mi < 4; ++mi)
#pragma unroll
            for (int nt = 0; nt < 4; ++nt)
                acco[mi][nt] += *(const f32x4*)(dA + ((mi * 4 + nt) * 64 + lane) * 4);
#pragma unroll
        for (int mi = 0; mi < 4; ++mi)
#pragma unroll
            for (int r = 0; r < 4; ++r) {
                const float inv = 1.0f / accl[mi][r];
                const int srow = qw + mi * 16 + quad * 4 + r;
                const int n = srow * BATCH + b;
#pragma unroll
                for (int nt = 0; nt < 4; ++nt)
                    Ao[(size_t)n * EMB + h * 64 + nt * 16 + l15] =
                        (__bf16)(acco[mi][nt][r] * inv);
            }
    }
}

// ---------------- host launch ----------------
extern "C" void kernel_launch(void* const* d_in, const int* in_sizes, int n_in,
                              void* d_out, int out_size, void* d_ws, size_t ws_size,
                              hipStream_t stream) {
    const float* x  = (const float*)d_in[0];
    const float* Wq = (const float*)d_in[1];
    const float* bq = (const float*)d_in[2];
    const float* Wk = (const float*)d_in[3];
    const float* bk = (const float*)d_in[4];
    const float* Wv = (const float*)d_in[5];
    const float* bv = (const float*)d_in[6];
    const float* Wo = (const float*)d_in[7];
    const float* bo = (const float*)d_in[8];
    float* out = (float*)d_out;

    char* ws = (char*)d_ws;
    const size_t xbf_sz = (size_t)NROW * EMB * 2;
    const size_t wbf_sz = (size_t)EMB * EMB * 2;
    const size_t qkv_sz = (size_t)BATCH * NH * S_LEN * HD * 2;
    __bf16* x_bf  = (__bf16*)ws;  ws += xbf_sz;
    __bf16* Wq_bf = (__bf16*)ws;  ws += wbf_sz;
    __bf16* Wk_bf = (__bf16*)ws;  ws += wbf_sz;
    __bf16* Wv_bf = (__bf16*)ws;  ws += wbf_sz;
    __bf16* Wo_bf = (__bf16*)ws;  ws += wbf_sz;
    __bf16* Qb    = (__bf16*)ws;  ws += qkv_sz;
    __bf16* Kb    = (__bf16*)ws;  ws += qkv_sz;
    __bf16* Vtb   = (__bf16*)ws;  ws += qkv_sz;
    __bf16* Aob   = (__bf16*)ws;  ws += qkv_sz;

    cvt_all_kernel<<<8192 + 4096, 256, 0, stream>>>(x, Wq, Wk, Wv, Wo,
                                                    x_bf, Wq_bf, Wk_bf, Wv_bf, Wo_bf);
    gemm_qkv_kernel<<<64 * 24, 256, 0, stream>>>(x_bf, Wq_bf, Wk_bf, Wv_bf,
                                                 bq, bk, bv, Qb, Kb, Vtb);
    dim3 ag(S_LEN / 128, BATCH * NH);
    attn_kernel<<<ag, 256, 0, stream>>>(Qb, Kb, Vtb, Aob);
    gemm_out_kernel<<<(NROW / 128) * (EMB / 128), 256, 0, stream>>>(Aob, Wo_bf, bo, out);
}